// Round 13
// baseline (94.240 us; speedup 1.0000x reference)
//
#include <hip/hip_runtime.h>

constexpr int B = 8, N = 16384, C = 80, M = 100;
constexpr int NT = 128;          // n per block
constexpr int THREADS = 256;     // 4 waves; wave owns 32 n (2 row-frags)
constexpr int NBLK = N / NT;     // 128 blocks per b -> 128 slots per b

typedef _Float16 half8 __attribute__((ext_vector_type(8)));
typedef float f32x4 __attribute__((ext_vector_type(4)));
typedef unsigned long long u64;

// ws layout (bytes):
//   ftab : [B][3][7][64] uint4        = 172032   @ 0        (ct as fp16 1.0)
//   ftab2: [B][3][7][64] uint4        = 172032   @ 172032   (ct as fp16 2^-11)
//   clsid: B*M ints                   =   3200   @ 344064
//   wred : [B][NBLK][112] u64         =  917504  @ 347264   (8-aligned)
constexpr size_t WS_FT   = 0;
constexpr size_t WS_FT2  = 172032;
constexpr size_t WS_CID  = 344064;
constexpr size_t WS_WRED = 347264;

__device__ __forceinline__ unsigned ford(float f) {
    unsigned u = __float_as_uint(f);
    return (u & 0x80000000u) ? ~u : (u | 0x80000000u);
}

__device__ __forceinline__ float rcpf(float x) { return __builtin_amdgcn_rcpf(x); }

// argmin-equivalent total: (true_total/2 - 1). Positive scale + constant
// shift preserve argmin. Guards via fmax-clamped rcp (exact in guard cases).
// eh/ew via min+max sum identity.
__device__ __forceinline__ float pair_total(float cls,
    float4 p, float4 t, float a1, float a2,
    float hp, float wp, float ht, float wt)
{
    float ih = fminf(p.z, t.z) - fmaxf(p.x, t.x);
    float iw = fminf(p.w, t.w) - fmaxf(p.y, t.y);
    float inter = fmaxf(ih, 0.f) * fmaxf(iw, 0.f);
    float uni = a1 + a2 - inter;
    float iou = inter * rcpf(fmaxf(uni, 1e-30f));
    float eh = hp + ht - ih;
    float ew = wp + wt - iw;
    float enc = fmaxf(eh, 0.f) * fmaxf(ew, 0.f);
    float ue = (enc - uni) * rcpf(fmaxf(enc, 1e-30f));
    float rg = fabsf(t.x - p.x) + fabsf(t.y - p.y) +
               fabsf(t.z - p.z) + fabsf(t.w - p.w);
    return fmaf(2.5f, rg, cls) + (ue - iou);
}

// split diff into fp16 hi + lo*2^-11 fragments for one row's 8-elem chunk
__device__ __forceinline__ void make_frags(const float* __restrict__ cpb,
                                           int arow, int cbase,
                                           half8* ah, half8* al)
{
    float4 v0 = *(const float4*)&cpb[(size_t)arow * 80 + cbase];
    float4 v1 = *(const float4*)&cpb[(size_t)arow * 80 + cbase + 4];
    float pv[8] = { v0.x, v0.y, v0.z, v0.w, v1.x, v1.y, v1.z, v1.w };
    half8 hh, ll;
    #pragma unroll
    for (int j = 0; j < 8; ++j) {
        float p = pv[j], q = 1.0f - p;
        // ln2 folded: 0.25*ln2, 0.75*ln2; v_log_f32 is native log2
        float pos = 0.17328680f * q * q * (-__log2f(p + 1e-8f));
        float neg = 0.51986040f * p * p * (-__log2f(q + 1e-8f));
        float d = pos - neg;
        _Float16 h = (_Float16)d;
        _Float16 r = (_Float16)((d - (float)h) * 2048.0f);
        hh[j] = h;
        ll[j] = r;
    }
    *ah = hh;
    *al = ll;
}

// Light prep: waves [0,B*21) build ftab+ftab2; waves [B*21,B*21+B*M) clsid.
__global__ void prep_light(const int* __restrict__ cls_true,
                           uint4* __restrict__ ftab,
                           uint4* __restrict__ ftab2,
                           int* __restrict__ clsid)
{
    int wid = (blockIdx.x * blockDim.x + threadIdx.x) >> 6;
    int l = threadIdx.x & 63;
    if (wid < B * 21) {
        int b = wid / 21, rem = wid % 21, ch = rem / 7, mf = rem % 7;
        int m = mf * 16 + (l & 15);
        int c0 = ch * 32 + (l >> 4) * 8;
        unsigned w[4] = {0, 0, 0, 0};
        if (m < M) {
            const int* row = cls_true + ((size_t)b * M + m) * C;
            #pragma unroll
            for (int e = 0; e < 8; ++e) {
                int c = c0 + e;
                unsigned h = (c < C && row[c] == 1) ? 0x3C00u : 0u;  // fp16 1.0
                w[e >> 1] |= h << ((e & 1) * 16);
            }
        }
        ftab[(size_t)wid * 64 + l] = make_uint4(w[0], w[1], w[2], w[3]);
        ftab2[(size_t)wid * 64 + l] =
            make_uint4(w[0] & 0x10001000u, w[1] & 0x10001000u,
                       w[2] & 0x10001000u, w[3] & 0x10001000u);  // fp16 2^-11
    } else if (wid < B * 21 + B * M) {
        int id = wid - B * 21;
        const int* row = cls_true + (size_t)id * C;
        bool v1 = (row[l] == 1);
        bool v2 = (l < 16) ? (row[64 + l] == 1) : false;
        u64 m01 = __ballot(v1);
        u64 m2  = __ballot(v2);
        if (l == 0) {
            int cid = 0;
            if (m01) cid = __ffsll(m01) - 1;
            else if (m2) cid = 64 + __ffsll(m2) - 1;
            clsid[id] = cid;
        }
    }
}

// 32 n per wave: 2 row-frags share each ftab load; two-pass epilogue.
__global__ __launch_bounds__(THREADS, 4)
void match_kernel(const float* __restrict__ cls_pred,
                  const float* __restrict__ loc_pred,
                  const uint4* __restrict__ ftab,
                  const uint4* __restrict__ ftab2,
                  const float* __restrict__ loc_true,
                  u64* __restrict__ wred)
{
    __shared__ u64 s_red[4][112];

    const int b  = blockIdx.y;
    const int n0 = blockIdx.x * NT;
    const int t  = threadIdx.x;
    const int l  = t & 63;
    const int wv = t >> 6;
    const int nw = wv * 32;

    f32x4 acc0[7], acc1[7];
    #pragma unroll
    for (int mf = 0; mf < 7; ++mf) {
        acc0[mf] = f32x4{0.f, 0.f, 0.f, 0.f};
        acc1[mf] = f32x4{0.f, 0.f, 0.f, 0.f};
    }

    const uint4* ft  = ftab  + (size_t)b * 21 * 64;
    const uint4* ft2 = ftab2 + (size_t)b * 21 * 64;
    const float* cpb = cls_pred + (size_t)b * N * 80;
    const int arow0 = n0 + nw + (l & 15);
    const int arow1 = arow0 + 16;

    #pragma unroll
    for (int kc = 0; kc < 3; ++kc) {
        const int cbase = kc * 32 + (l >> 4) * 8;
        half8 ah0 = {0,0,0,0,0,0,0,0}, al0 = {0,0,0,0,0,0,0,0};
        half8 ah1 = {0,0,0,0,0,0,0,0}, al1 = {0,0,0,0,0,0,0,0};
        if (cbase < 80) {
            make_frags(cpb, arow0, cbase, &ah0, &al0);
            make_frags(cpb, arow1, cbase, &ah1, &al1);
        }
        #pragma unroll
        for (int mf = 0; mf < 7; ++mf) {
            union { uint4 u; half8 h; } b1, b2;
            b1.u = ft [((size_t)kc * 7 + mf) * 64 + l];
            b2.u = ft2[((size_t)kc * 7 + mf) * 64 + l];
            acc0[mf] = __builtin_amdgcn_mfma_f32_16x16x32_f16(ah0, b1.h, acc0[mf], 0, 0, 0);
            acc0[mf] = __builtin_amdgcn_mfma_f32_16x16x32_f16(al0, b2.h, acc0[mf], 0, 0, 0);
            acc1[mf] = __builtin_amdgcn_mfma_f32_16x16x32_f16(ah1, b1.h, acc1[mf], 0, 0, 0);
            acc1[mf] = __builtin_amdgcn_mfma_f32_16x16x32_f16(al1, b2.h, acc1[mf], 0, 0, 0);
        }
    }

    u64 key[7];

    // ---- pass nf=0: rows nbase0..+3 ----
    {
        const int nbase = n0 + nw + (l >> 4) * 4;
        float4 bx[4];
        float a1[4], hp[4], wp[4];
        #pragma unroll
        for (int r = 0; r < 4; ++r) {
            float4 v = ((const float4*)loc_pred)[(size_t)b * N + nbase + r];
            bx[r] = v;
            hp[r] = v.z - v.x;
            wp[r] = v.w - v.y;
            a1[r] = fmaxf(hp[r], 0.f) * fmaxf(wp[r], 0.f);
        }
        #pragma unroll
        for (int mf = 0; mf < 7; ++mf) {
            int m = mf * 16 + (l & 15);
            int mm = (m < M) ? m : (M - 1);
            float4 tb = ((const float4*)loc_true)[(size_t)b * M + mm];
            float ht = tb.z - tb.x, wt = tb.w - tb.y;
            float a2 = fmaxf(ht, 0.f) * fmaxf(wt, 0.f);
            float v = pair_total(acc0[mf][0], bx[0], tb, a1[0], a2, hp[0], wp[0], ht, wt);
            unsigned ni = (unsigned)nbase;
            #pragma unroll
            for (int r = 1; r < 4; ++r) {
                float tr = pair_total(acc0[mf][r], bx[r], tb, a1[r], a2, hp[r], wp[r], ht, wt);
                bool c = tr < v;
                v = c ? tr : v;
                ni = c ? (unsigned)(nbase + r) : ni;
            }
            key[mf] = ((u64)ford(v) << 32) | ni;
        }
    }

    // ---- pass nf=1: rows nbase1..+3 ----
    {
        const int nbase = n0 + nw + 16 + (l >> 4) * 4;
        float4 bx[4];
        float a1[4], hp[4], wp[4];
        #pragma unroll
        for (int r = 0; r < 4; ++r) {
            float4 v = ((const float4*)loc_pred)[(size_t)b * N + nbase + r];
            bx[r] = v;
            hp[r] = v.z - v.x;
            wp[r] = v.w - v.y;
            a1[r] = fmaxf(hp[r], 0.f) * fmaxf(wp[r], 0.f);
        }
        #pragma unroll
        for (int mf = 0; mf < 7; ++mf) {
            int m = mf * 16 + (l & 15);
            int mm = (m < M) ? m : (M - 1);
            float4 tb = ((const float4*)loc_true)[(size_t)b * M + mm];
            float ht = tb.z - tb.x, wt = tb.w - tb.y;
            float a2 = fmaxf(ht, 0.f) * fmaxf(wt, 0.f);
            float v = pair_total(acc1[mf][0], bx[0], tb, a1[0], a2, hp[0], wp[0], ht, wt);
            unsigned ni = (unsigned)nbase;
            #pragma unroll
            for (int r = 1; r < 4; ++r) {
                float tr = pair_total(acc1[mf][r], bx[r], tb, a1[r], a2, hp[r], wp[r], ht, wt);
                bool c = tr < v;
                v = c ? tr : v;
                ni = c ? (unsigned)(nbase + r) : ni;
            }
            u64 cand = ((u64)ford(v) << 32) | ni;
            key[mf] = (cand < key[mf]) ? cand : key[mf];
        }
    }

    // ---- cross-lane reduce (lane bits 4,5) + LDS combine ----
    #pragma unroll
    for (int mf = 0; mf < 7; ++mf) {
        u64 k = key[mf];
        #pragma unroll
        for (int off = 16; off <= 32; off <<= 1) {
            u64 o = __shfl_xor(k, off, 64);
            k = (o < k) ? o : k;
        }
        if (l < 16) s_red[wv][mf * 16 + l] = k;
    }
    __syncthreads();

    if (t < 112) {
        u64 v0 = s_red[0][t], v1 = s_red[1][t];
        u64 v2 = s_red[2][t], v3 = s_red[3][t];
        u64 a = v0 < v1 ? v0 : v1;
        u64 c = v2 < v3 ? v2 : v3;
        a = a < c ? a : c;
        wred[((size_t)b * NBLK + blockIdx.x) * 112 + t] = a;
    }
}

// Final: one wave per (b,m); 64 lanes x 2 slots = 128 slots, shuffle reduce.
__global__ __launch_bounds__(64)
void reduce_kernel(const u64* __restrict__ wred,
                   const int* __restrict__ clsid,
                   int* __restrict__ out)
{
    const int bm = blockIdx.x;
    const int b = bm / M, m = bm % M;
    const int l = threadIdx.x;

    const u64* base = wred + (size_t)b * NBLK * 112 + m;
    u64 k0 = base[(size_t)l * 112];
    u64 k1 = base[(size_t)(l + 64) * 112];
    u64 best = (k0 < k1) ? k0 : k1;
    #pragma unroll
    for (int off = 1; off < 64; off <<= 1) {
        u64 o = __shfl_xor(best, off, 64);
        best = (o < best) ? o : best;
    }
    if (l == 0) {
        out[bm * 3 + 0] = b;
        out[bm * 3 + 1] = (int)(unsigned)(best & 0xFFFFFFFFull);
        out[bm * 3 + 2] = clsid[bm];
    }
}

extern "C" void kernel_launch(void* const* d_in, const int* in_sizes, int n_in,
                              void* d_out, int out_size, void* d_ws, size_t ws_size,
                              hipStream_t stream)
{
    const float* cls_pred = (const float*)d_in[0];
    const float* loc_pred = (const float*)d_in[1];
    const int*   cls_true = (const int*)d_in[2];
    const float* loc_true = (const float*)d_in[3];

    char* ws = (char*)d_ws;
    uint4* ftab  = (uint4*)(ws + WS_FT);
    uint4* ftab2 = (uint4*)(ws + WS_FT2);
    int*   clsid = (int*)(ws + WS_CID);
    u64*   wred  = (u64*)(ws + WS_WRED);
    int* out = (int*)d_out;

    int prep_waves = B * 21 + B * M;   // 968
    prep_light<<<(prep_waves * 64 + 255) / 256, 256, 0, stream>>>(
        cls_true, ftab, ftab2, clsid);

    dim3 grid(NBLK, B);
    match_kernel<<<grid, THREADS, 0, stream>>>(
        cls_pred, loc_pred, ftab, ftab2, loc_true, wred);

    reduce_kernel<<<B * M, 64, 0, stream>>>(wred, clsid, out);
}

// Round 14
// 45.677 us; speedup vs baseline: 2.0632x; 2.0632x over previous
//
#include <hip/hip_runtime.h>

constexpr int B = 8, N = 16384, C = 80, M = 100;
constexpr int NT = 64;           // n per block
constexpr int THREADS = 256;     // 4 waves
constexpr int NBLK = N / NT;     // 256 blocks per b -> 256 slots per b
constexpr int NFRAG = 21 * 64;   // 1344 uint4 = 21.5 KB ftab per batch

typedef _Float16 half8 __attribute__((ext_vector_type(8)));
typedef float f32x4 __attribute__((ext_vector_type(4)));
typedef unsigned long long u64;

// ws layout (bytes):
//   ftab : [B][3][7][64] uint4        = 172032   @ 0        (ct as fp16 1.0)
//   clsid: B*M ints                   =   3200   @ 172032
//   wred : [B][NBLK][112] u64         = 1835008  @ 175232   (8-aligned)
constexpr size_t WS_FT   = 0;
constexpr size_t WS_CID  = 172032;
constexpr size_t WS_WRED = 175232;

__device__ __forceinline__ unsigned ford(float f) {
    unsigned u = __float_as_uint(f);
    return (u & 0x80000000u) ? ~u : (u | 0x80000000u);
}

__device__ __forceinline__ float rcpf(float x) { return __builtin_amdgcn_rcpf(x); }

// argmin-equivalent total: (true_total/2 - 1). Positive scale + constant
// shift preserve argmin. Guards via fmax-clamped rcp (exact in guard cases).
// eh/ew via min+max sum identity.
__device__ __forceinline__ float pair_total(float cls,
    float4 p, float4 t, float a1, float a2,
    float hp, float wp, float ht, float wt)
{
    float ih = fminf(p.z, t.z) - fmaxf(p.x, t.x);
    float iw = fminf(p.w, t.w) - fmaxf(p.y, t.y);
    float inter = fmaxf(ih, 0.f) * fmaxf(iw, 0.f);
    float uni = a1 + a2 - inter;
    float iou = inter * rcpf(fmaxf(uni, 1e-30f));
    float eh = hp + ht - ih;
    float ew = wp + wt - iw;
    float enc = fmaxf(eh, 0.f) * fmaxf(ew, 0.f);
    float ue = (enc - uni) * rcpf(fmaxf(enc, 1e-30f));
    float rg = fabsf(t.x - p.x) + fabsf(t.y - p.y) +
               fabsf(t.z - p.z) + fabsf(t.w - p.w);
    return fmaf(2.5f, rg, cls) + (ue - iou);
}

// fp16 hi + lo*2^-11 split of diff for one row's 8-elem chunk (values in)
__device__ __forceinline__ void make_frags(float4 v0, float4 v1,
                                           half8* ah, half8* al)
{
    float pv[8] = { v0.x, v0.y, v0.z, v0.w, v1.x, v1.y, v1.z, v1.w };
    half8 hh, ll;
    #pragma unroll
    for (int j = 0; j < 8; ++j) {
        float p = pv[j], q = 1.0f - p;
        // ln2 folded: 0.25*ln2, 0.75*ln2; v_log_f32 is native log2
        float pos = 0.17328680f * q * q * (-__log2f(p + 1e-8f));
        float neg = 0.51986040f * p * p * (-__log2f(q + 1e-8f));
        float d = pos - neg;
        _Float16 h = (_Float16)d;
        _Float16 r = (_Float16)((d - (float)h) * 2048.0f);
        hh[j] = h;
        ll[j] = r;
    }
    *ah = hh;
    *al = ll;
}

// Light prep: waves [0,B*21) build ftab; waves [B*21,B*21+B*M) clsid.
__global__ void prep_light(const int* __restrict__ cls_true,
                           uint4* __restrict__ ftab,
                           int* __restrict__ clsid)
{
    int wid = (blockIdx.x * blockDim.x + threadIdx.x) >> 6;
    int l = threadIdx.x & 63;
    if (wid < B * 21) {
        int b = wid / 21, rem = wid % 21, ch = rem / 7, mf = rem % 7;
        int m = mf * 16 + (l & 15);
        int c0 = ch * 32 + (l >> 4) * 8;
        unsigned w[4] = {0, 0, 0, 0};
        if (m < M) {
            const int* row = cls_true + ((size_t)b * M + m) * C;
            #pragma unroll
            for (int e = 0; e < 8; ++e) {
                int c = c0 + e;
                unsigned h = (c < C && row[c] == 1) ? 0x3C00u : 0u;  // fp16 1.0
                w[e >> 1] |= h << ((e & 1) * 16);
            }
        }
        ftab[(size_t)wid * 64 + l] = make_uint4(w[0], w[1], w[2], w[3]);
    } else if (wid < B * 21 + B * M) {
        int id = wid - B * 21;
        const int* row = cls_true + (size_t)id * C;
        bool v1 = (row[l] == 1);
        bool v2 = (l < 16) ? (row[64 + l] == 1) : false;
        u64 m01 = __ballot(v1);
        u64 m2  = __ballot(v2);
        if (l == 0) {
            int cid = 0;
            if (m01) cid = __ffsll(m01) - 1;
            else if (m2) cid = 64 + __ffsll(m2) - 1;
            clsid[id] = cid;
        }
    }
}

// ftab staged once per block into LDS (shared by 4 waves); ftab2 regenerated
// via v_and; A-loads hoisted above staging so L2 latency hides under it.
__global__ __launch_bounds__(THREADS, 4)
void match_kernel(const float* __restrict__ cls_pred,
                  const float* __restrict__ loc_pred,
                  const uint4* __restrict__ ftab,
                  const float* __restrict__ loc_true,
                  u64* __restrict__ wred)
{
    __shared__ uint4 s_ft[NFRAG];     // 21504 B
    __shared__ u64 s_red[4][112];     //  3584 B

    const int b  = blockIdx.y;
    const int n0 = blockIdx.x * NT;
    const int t  = threadIdx.x;
    const int l  = t & 63;
    const int wv = t >> 6;
    const int nw = wv * 16;

    const float* cpb = cls_pred + (size_t)b * N * 80;
    const int arow = n0 + nw + (l & 15);

    // hoisted A-loads (latency overlaps staging below)
    float4 av0[3], av1[3];
    #pragma unroll
    for (int kc = 0; kc < 3; ++kc) {
        const int cbase = kc * 32 + (l >> 4) * 8;
        if (cbase < 80) {
            av0[kc] = *(const float4*)&cpb[(size_t)arow * 80 + cbase];
            av1[kc] = *(const float4*)&cpb[(size_t)arow * 80 + cbase + 4];
        }
    }

    // stage ftab for this batch into LDS (reg-staged, 6 iters)
    const uint4* ftb = ftab + (size_t)b * NFRAG;
    for (int i = t; i < NFRAG; i += THREADS) s_ft[i] = ftb[i];
    __syncthreads();

    f32x4 acc[7];
    #pragma unroll
    for (int mf = 0; mf < 7; ++mf) acc[mf] = f32x4{0.f, 0.f, 0.f, 0.f};

    #pragma unroll
    for (int kc = 0; kc < 3; ++kc) {
        const int cbase = kc * 32 + (l >> 4) * 8;
        half8 ah = {0,0,0,0,0,0,0,0}, al = {0,0,0,0,0,0,0,0};
        if (cbase < 80) make_frags(av0[kc], av1[kc], &ah, &al);
        #pragma unroll
        for (int mf = 0; mf < 7; ++mf) {
            union { uint4 u; half8 h; } b1, b2;
            b1.u = s_ft[(kc * 7 + mf) * 64 + l];
            b2.u = make_uint4(b1.u.x & 0x10001000u, b1.u.y & 0x10001000u,
                              b1.u.z & 0x10001000u, b1.u.w & 0x10001000u);
            acc[mf] = __builtin_amdgcn_mfma_f32_16x16x32_f16(ah, b1.h, acc[mf], 0, 0, 0);
            acc[mf] = __builtin_amdgcn_mfma_f32_16x16x32_f16(al, b2.h, acc[mf], 0, 0, 0);
        }
    }

    // per-lane 4 n-boxes (consecutive rows)
    const int nbase = n0 + nw + (l >> 4) * 4;
    float4 bx[4];
    float a1[4], hp[4], wp[4];
    #pragma unroll
    for (int r = 0; r < 4; ++r) {
        float4 v = ((const float4*)loc_pred)[(size_t)b * N + nbase + r];
        bx[r] = v;
        hp[r] = v.z - v.x;
        wp[r] = v.w - v.y;
        a1[r] = fmaxf(hp[r], 0.f) * fmaxf(wp[r], 0.f);
    }

    #pragma unroll
    for (int mf = 0; mf < 7; ++mf) {
        int m = mf * 16 + (l & 15);
        int mm = (m < M) ? m : (M - 1);
        float4 tb = ((const float4*)loc_true)[(size_t)b * M + mm];
        float ht = tb.z - tb.x, wt = tb.w - tb.y;
        float a2 = fmaxf(ht, 0.f) * fmaxf(wt, 0.f);
        float tot[4];
        #pragma unroll
        for (int r = 0; r < 4; ++r)
            tot[r] = pair_total(acc[mf][r], bx[r], tb, a1[r], a2,
                                hp[r], wp[r], ht, wt);
        // in-lane argmin over r (ascending n; strict < = first occurrence)
        float v = tot[0];
        unsigned ni = (unsigned)nbase;
        #pragma unroll
        for (int r = 1; r < 4; ++r) {
            bool c = tot[r] < v;
            v = c ? tot[r] : v;
            ni = c ? (unsigned)(nbase + r) : ni;
        }
        // u64 key: lex (ordered-float, n) -> min = (min val, then min n)
        u64 key = ((u64)ford(v) << 32) | ni;
        #pragma unroll
        for (int off = 16; off <= 32; off <<= 1) {
            u64 o = __shfl_xor(key, off, 64);
            key = (o < key) ? o : key;
        }
        if (l < 16) s_red[wv][m] = key;
    }
    __syncthreads();

    // 4-wave combine, one u64 store per m per block
    if (t < 112) {
        u64 v0 = s_red[0][t], v1 = s_red[1][t];
        u64 v2 = s_red[2][t], v3 = s_red[3][t];
        u64 a = v0 < v1 ? v0 : v1;
        u64 c = v2 < v3 ? v2 : v3;
        a = a < c ? a : c;
        wred[((size_t)b * NBLK + blockIdx.x) * 112 + t] = a;
    }
}

// Final: one block per (b,m); 256 threads = 256 slots, one load each.
__global__ __launch_bounds__(256)
void reduce_kernel(const u64* __restrict__ wred,
                   const int* __restrict__ clsid,
                   int* __restrict__ out)
{
    __shared__ u64 s_part[4];
    const int bm = blockIdx.x;
    const int b = bm / M, m = bm % M;
    const int t = threadIdx.x, l = t & 63, wv = t >> 6;

    u64 best = wred[((size_t)b * NBLK + t) * 112 + m];
    #pragma unroll
    for (int off = 1; off < 64; off <<= 1) {
        u64 o = __shfl_xor(best, off, 64);
        best = (o < best) ? o : best;
    }
    if (l == 0) s_part[wv] = best;
    __syncthreads();
    if (t == 0) {
        u64 a0 = s_part[0], a1 = s_part[1];
        u64 a2 = s_part[2], a3 = s_part[3];
        u64 a = a0 < a1 ? a0 : a1;
        u64 c = a2 < a3 ? a2 : a3;
        a = a < c ? a : c;
        out[bm * 3 + 0] = b;
        out[bm * 3 + 1] = (int)(unsigned)(a & 0xFFFFFFFFull);
        out[bm * 3 + 2] = clsid[bm];
    }
}

extern "C" void kernel_launch(void* const* d_in, const int* in_sizes, int n_in,
                              void* d_out, int out_size, void* d_ws, size_t ws_size,
                              hipStream_t stream)
{
    const float* cls_pred = (const float*)d_in[0];
    const float* loc_pred = (const float*)d_in[1];
    const int*   cls_true = (const int*)d_in[2];
    const float* loc_true = (const float*)d_in[3];

    char* ws = (char*)d_ws;
    uint4* ftab  = (uint4*)(ws + WS_FT);
    int*   clsid = (int*)(ws + WS_CID);
    u64*   wred  = (u64*)(ws + WS_WRED);
    int* out = (int*)d_out;

    int prep_waves = B * 21 + B * M;   // 968
    prep_light<<<(prep_waves * 64 + 255) / 256, 256, 0, stream>>>(
        cls_true, ftab, clsid);

    dim3 grid(NBLK, B);
    match_kernel<<<grid, THREADS, 0, stream>>>(
        cls_pred, loc_pred, ftab, loc_true, wred);

    reduce_kernel<<<B * M, 256, 0, stream>>>(wred, clsid, out);
}